// Round 1
// baseline (563.759 us; speedup 1.0000x reference)
//
#include <hip/hip_runtime.h>

// Problem constants
#define N_ROWS   32768      // 64*512 flattened z rows
#define KCODES   1024
#define DDIM     256
#define RPB      64         // rows per argmin block: As=64KB -> 2 blocks/CU
#define NBLK     512        // 32768/64

// d_out float offsets (outputs concatenated in reference return order)
#define O_ZQ     0                    // 8388608
#define O_LOSS   8388608              // 1
#define O_IDX    8388609              // 32768
#define O_NCS    8421377              // 1024
#define O_NEA    8422401              // 262144
#define O_NEMB   8684545              // 262144

// workspace float offsets
#define W_ESUM   0                    // 262144 (memset, together with CNT)
#define W_CNT    262144               // 1024 ints (memset)
#define W_ENORM  263168               // 1024
#define W_LOSSP  264192               // 512
#define W_CUR    264704               // 1024 ints
#define W_N      265728               // 1
#define W_IDX    265792               // 32768 ints
#define W_SORT   298560               // 32768 ints

typedef _Float16 half_t;
typedef __attribute__((ext_vector_type(8))) _Float16 half8;
typedef __attribute__((ext_vector_type(4))) float floatx4;

// ---------------------------------------------------------------------------
// Pack B into MFMA-native fragment order + compute ||e||^2.
// Bp[ct][pk][lane][8]: ct = 16-code tile (64 tiles), pk = packed k-step
// (16 = seg0 hi + seg1 lo; phase 16..23 reuses pk 0..7 -> 1MB total),
// lane: col=lane&15 (code), k = (lane>>4)*8 + j.
__global__ __launch_bounds__(256)
void k_prep2(const float* __restrict__ emb, float* __restrict__ enorm,
             half_t* __restrict__ Bp) {
    __shared__ half_t hi[16 * 256];
    __shared__ half_t lo[16 * 256];
    __shared__ float  ssum[256];
    const int ct  = blockIdx.x;       // 16-code tile
    const int tid = threadIdx.x;
    const int c16 = tid >> 4;         // code within tile
    const int dp  = tid & 15;         // 16-dim part

    float ss = 0.f;
    #pragma unroll
    for (int i = 0; i < 4; ++i) {
        float4 v = *(const float4*)(emb + (size_t)(ct * 16 + c16) * DDIM + dp * 16 + i * 4);
        ss += v.x * v.x + v.y * v.y + v.z * v.z + v.w * v.w;
        #pragma unroll
        for (int q = 0; q < 4; ++q) {
            float f = (&v.x)[q];
            half_t h = (half_t)f;
            hi[c16 * 256 + dp * 16 + i * 4 + q] = h;
            lo[c16 * 256 + dp * 16 + i * 4 + q] = (half_t)(f - (float)h);
        }
    }
    ssum[tid] = ss;
    __syncthreads();
    if (tid < 16) {
        float s = 0.f;
        #pragma unroll
        for (int i = 0; i < 16; ++i) s += ssum[tid * 16 + i];
        enorm[ct * 16 + tid] = s;
    }

    // write phase: 16 packed steps x 64 lanes x 8 halfs
    #pragma unroll
    for (int i = 0; i < 4; ++i) {
        int f    = tid + i * 256;     // 0..1023
        int ks   = f >> 6;            // 0..15
        int lane = f & 63;
        int cc   = lane & 15;
        int seg  = ks >> 3;           // 0:hi 1:lo
        int ko   = (ks & 7) * 32 + (lane >> 4) * 8;
        const half_t* src = (seg == 1) ? lo : hi;
        half8 v = *(const half8*)(src + cc * 256 + ko);
        *(half8*)(Bp + ((size_t)(ct * 16 + ks) * 64 + lane) * 8) = v;
    }
}

// ---------------------------------------------------------------------------
// MFMA argmin. dist(r,c)=||e||^2-2 z.e; fp16 hi/lo K-concat (K'=768):
// phase c=0: z_hi.e_hi, c=1: z_hi.e_lo, c=2: z_lo.e_hi (B reuses pk 0..7).
// R8 restructure: 512 threads = 8 waves/block; per-wave tile halved to
// 32 rows x 256 codes (acc[2][4]=32 VGPR, ping-pong B prefetch=32 VGPR)
// so the whole working set fits 128 VGPR -> __launch_bounds__(512,4)
// gives 4 waves/SIMD (2 blocks/CU, 16 waves/CU) vs previous 2 waves/SIMD
// at VGPR=256. Previous spill failures (R5/R7) were with the 176+-reg
// 64x256 tile; the halved tile genuinely fits the 128 cap.
__global__ __launch_bounds__(512, 4)
void k_argmin(const float* __restrict__ z, const half_t* __restrict__ Bp,
              const float* __restrict__ enorm, const float* __restrict__ embf,
              int* __restrict__ out_idx, float* __restrict__ out_idx_f,
              float* __restrict__ out_zq, float* __restrict__ lossp,
              int* __restrict__ counts_i) {
    __shared__ __align__(16) half_t As[RPB * 512];   // 64 KB

    const int tid  = threadIdx.x;
    const int w    = tid >> 6;        // 0..7
    const int lane = tid & 63;
    const int tx   = lane & 15;
    const int quad = lane >> 4;
    const int rh   = w >> 2;          // row half: 0 -> rows 0..31, 1 -> 32..63
    const int cq   = w & 3;           // code quarter: codes [cq*256, cq*256+256)
    const int rbase = blockIdx.x * RPB;

    // ---- stage A: read z fp32, split hi/lo in-register, swizzled LDS store
    #pragma unroll
    for (int it = 0; it < 4; ++it) {
        int f   = tid + it * 512;
        int row = f >> 5;             // 0..63
        int g   = f & 31;
        const float* zp = z + (size_t)(rbase + row) * DDIM + g * 8;
        float4 v0 = *(const float4*)zp;
        float4 v1 = *(const float4*)(zp + 4);
        half8 hi, lo;
        hi[0] = (half_t)v0.x; lo[0] = (half_t)(v0.x - (float)hi[0]);
        hi[1] = (half_t)v0.y; lo[1] = (half_t)(v0.y - (float)hi[1]);
        hi[2] = (half_t)v0.z; lo[2] = (half_t)(v0.z - (float)hi[2]);
        hi[3] = (half_t)v0.w; lo[3] = (half_t)(v0.w - (float)hi[3]);
        hi[4] = (half_t)v1.x; lo[4] = (half_t)(v1.x - (float)hi[4]);
        hi[5] = (half_t)v1.y; lo[5] = (half_t)(v1.y - (float)hi[5]);
        hi[6] = (half_t)v1.z; lo[6] = (half_t)(v1.z - (float)hi[6]);
        hi[7] = (half_t)v1.w; lo[7] = (half_t)(v1.w - (float)hi[7]);
        int sw = row & 7;
        *(half8*)(&As[row * 512 + ((g ^ sw)) * 8])        = hi;  // k8 = g
        *(half8*)(&As[row * 512 + (((32 + g) ^ sw)) * 8]) = lo;  // k8 = 32+g
    }
    __syncthreads();                  // the ONLY main-loop barrier

    floatx4 zero4 = {0.f, 0.f, 0.f, 0.f};
    float bd[2][4];
    int   bi[2][4];
    #pragma unroll
    for (int mt = 0; mt < 2; ++mt)
        #pragma unroll
        for (int r = 0; r < 4; ++r) { bd[mt][r] = 3.402823466e38f; bi[mt][r] = 0; }

    for (int g4 = 0; g4 < 4; ++g4) {
        const int cb = cq * 256 + g4 * 64;
        // wave's 4 tiles this group: global ct = cq*16 + g4*4 + ns
        // Bp layout: ct stride 8192 halfs, pk stride 512, lane stride 8
        const half_t* Bg = Bp + (size_t)(cq * 16 + g4 * 4) * 8192 + lane * 8;

        floatx4 acc[2][4];
        #pragma unroll
        for (int mt = 0; mt < 2; ++mt)
            #pragma unroll
            for (int ns = 0; ns < 4; ++ns) acc[mt][ns] = zero4;

        half8 B0[4], B1[4];
        // phase P -> packed index (phases 16..23 reuse 0..7, L2-warm)
        #define LOADB(P, BUF)                                                  \
            { const int pk_ = ((P) < 16) ? (P) : ((P) - 16);                   \
              _Pragma("unroll")                                                \
              for (int ns = 0; ns < 4; ++ns)                                   \
                  BUF[ns] = *(const half8*)(Bg + (size_t)(ns * 16 + pk_) * 512); }
        LOADB(0, B0);
        LOADB(1, B1);

        #pragma unroll
        for (int ks = 0; ks < 24; ++ks) {
            const int c   = ks >> 3;
            const int k8b = (c == 2 ? 32 : 0) + (ks & 7) * 4;
            half8 a[2];
            #pragma unroll
            for (int mt = 0; mt < 2; ++mt) {
                int row = rh * 32 + mt * 16 + tx;
                a[mt] = *(half8*)(&As[row * 512 + ((k8b + quad) ^ (row & 7)) * 8]);
            }
            #pragma unroll
            for (int mt = 0; mt < 2; ++mt)
                #pragma unroll
                for (int ns = 0; ns < 4; ++ns) {
                    const half8& bb = (ks & 1) ? B1[ns] : B0[ns];
                    acc[mt][ns] = __builtin_amdgcn_mfma_f32_16x16x32_f16(a[mt], bb, acc[mt][ns], 0, 0, 0);
                }
            // ping-pong prefetch: refill the buffer just consumed (WAR on
            // regs keeps ordering); arrives during step ks+1, used at ks+2.
            if (ks + 2 < 24) {
                if (ks & 1) { LOADB(ks + 2, B1); }
                else        { LOADB(ks + 2, B0); }
            }
        }
        #undef LOADB

        // fold group into running argmin (codes ascending; strict <, min-index)
        #pragma unroll
        for (int ns = 0; ns < 4; ++ns) {
            float en = enorm[cb + ns * 16 + tx];
            int   cc = cb + ns * 16 + tx;
            #pragma unroll
            for (int mt = 0; mt < 2; ++mt)
                #pragma unroll
                for (int r = 0; r < 4; ++r) {
                    float d = fmaf(-2.f, acc[mt][ns][r], en);
                    if (d < bd[mt][r]) { bd[mt][r] = d; bi[mt][r] = cc; }
                }
        }
    }

    // reduce across 16 tx lanes (same row, different codes); ties -> min index
    #pragma unroll
    for (int mt = 0; mt < 2; ++mt)
        #pragma unroll
        for (int r = 0; r < 4; ++r) {
            float d = bd[mt][r];
            int   b = bi[mt][r];
            #pragma unroll
            for (int off = 8; off > 0; off >>= 1) {
                float od = __shfl_xor(d, off);
                int   ob = __shfl_xor(b, off);
                if (od < d || (od == d && ob < b)) { d = od; b = ob; }
            }
            bd[mt][r] = d; bi[mt][r] = b;
        }

    // cross-wave reduce via LDS (reuse As): per row, 4 code-quarter candidates
    __syncthreads();
    float* sd   = (float*)As;          // [64 rows][4 quarters]
    int*   si   = ((int*)As) + 256;
    int*   sidx = ((int*)As) + 512;    // final idx per row
    if (tx == 0) {
        #pragma unroll
        for (int mt = 0; mt < 2; ++mt)
            #pragma unroll
            for (int r = 0; r < 4; ++r) {
                int row = rh * 32 + mt * 16 + quad * 4 + r;  // C-layout: row = quad*4+reg
                sd[row * 4 + cq] = bd[mt][r];
                si[row * 4 + cq] = bi[mt][r];
            }
    }
    __syncthreads();
    if (tid < RPB) {
        int row = tid;
        float d = sd[row * 4];
        int   b = si[row * 4];
        #pragma unroll
        for (int ww = 1; ww < 4; ++ww) {
            float od = sd[row * 4 + ww];
            int   ob = si[row * 4 + ww];
            if (od < d || (od == d && ob < b)) { d = od; b = ob; }
        }
        sidx[row] = b;
        out_idx[rbase + row]   = b;
        out_idx_f[rbase + row] = (float)b;
        atomicAdd(&counts_i[b], 1);
    }
    __syncthreads();

    // ---- fused z_q epilogue: z_q_st write + commitment-loss partial
    float l = 0.f;
    #pragma unroll
    for (int u = 0; u < 8; ++u) {
        int gi  = tid + u * 512;       // 0..4095 float4s = 64 rows x 64
        int row = gi >> 6;
        int c4  = gi & 63;
        int k   = sidx[row];           // wave-uniform
        float4 zv = *(const float4*)(z    + (size_t)(rbase + row) * DDIM + c4 * 4);
        float4 ev = *(const float4*)(embf + (size_t)k * DDIM + c4 * 4);
        float dx = ev.x - zv.x, dy = ev.y - zv.y, dz = ev.z - zv.z, dw = ev.w - zv.w;
        float4 o = { zv.x + dx, zv.y + dy, zv.z + dz, zv.w + dw };  // z + (z_q - z)
        *(float4*)(out_zq + (size_t)(rbase + row) * DDIM + c4 * 4) = o;
        l += dx * dx + dy * dy + dz * dz + dw * dw;
    }
    #pragma unroll
    for (int off = 32; off > 0; off >>= 1) l += __shfl_down(l, off);
    __shared__ float ls[8];
    if (lane == 0) ls[w] = l;
    __syncthreads();
    if (tid == 0) {
        float s = 0.f;
        #pragma unroll
        for (int i = 0; i < 8; ++i) s += ls[i];
        lossp[blockIdx.x] = s;
    }
}

// ---------------------------------------------------------------------------
// Single block: prefix-sum counts -> cursors; ncs/n/loss finalization.
__global__ __launch_bounds__(256)
void k_scan(const float* __restrict__ cs_in, const int* __restrict__ counts_i,
            const float* __restrict__ lossp, float* __restrict__ out_ncs,
            int* __restrict__ cursors,
            float* __restrict__ n_out, float* __restrict__ loss_out) {
    const int tid = threadIdx.x;
    __shared__ int ps[256];
    int c[4]; int pt = 0;
    #pragma unroll
    for (int i = 0; i < 4; ++i) { c[i] = counts_i[tid * 4 + i]; pt += c[i]; }
    ps[tid] = pt;
    __syncthreads();
    for (int s = 1; s < 256; s <<= 1) {
        int v = (tid >= s) ? ps[tid - s] : 0;
        __syncthreads();
        ps[tid] += v;
        __syncthreads();
    }
    int o = ps[tid] - pt;              // exclusive base for this thread's 4 bins
    float v = 0.f;
    #pragma unroll
    for (int i = 0; i < 4; ++i) {
        cursors[tid * 4 + i] = o;
        o += c[i];
        float nc = cs_in[tid * 4 + i] * 0.99f + 0.01f * (float)c[i];
        out_ncs[tid * 4 + i] = nc;
        v += nc;
    }
    float l = 0.f;
    for (int i = tid; i < NBLK; i += 256) l += lossp[i];
    #pragma unroll
    for (int off = 32; off > 0; off >>= 1) {
        v += __shfl_down(v, off);
        l += __shfl_down(l, off);
    }
    __shared__ float sv[4], sl[4];
    if ((tid & 63) == 0) { sv[tid >> 6] = v; sl[tid >> 6] = l; }
    __syncthreads();
    if (tid == 0) {
        n_out[0]    = sv[0] + sv[1] + sv[2] + sv[3];
        loss_out[0] = 0.25f * ((sl[0] + sl[1] + sl[2] + sl[3]) / 8388608.0f);
    }
}

// ---------------------------------------------------------------------------
// Scatter row ids into per-code contiguous lists (counting sort, phase 2).
__global__ __launch_bounds__(256)
void k_rank(const int* __restrict__ idx, int* __restrict__ cursors,
            int* __restrict__ rows_sorted) {
    int r = blockIdx.x * 256 + threadIdx.x;
    int k = idx[r];
    int pos = atomicAdd(&cursors[k], 1);
    rows_sorted[pos] = r;
}

// ---------------------------------------------------------------------------
// Skew-proof segment-sum: each wave owns exactly 64 sorted positions,
// accumulates equal-code runs in registers, flushes runs via fp32 atomics.
__global__ __launch_bounds__(128)
void k_esum2(const float* __restrict__ z, const int* __restrict__ rows_sorted,
             const int* __restrict__ idx, float* __restrict__ esum) {
    const int tid  = threadIdx.x;
    const int w    = tid >> 6;
    const int lane = tid & 63;
    const int base = (blockIdx.x * 2 + w) * 64;   // 256 blocks x 2 waves

    int r = rows_sorted[base + lane];
    int c = idx[r];
    float4 acc = {0.f, 0.f, 0.f, 0.f};
    #pragma unroll 8
    for (int j = 0; j < 64; ++j) {
        int rj = __shfl(r, j);
        int cj = __shfl(c, j);
        float4 zv = *(const float4*)(z + (size_t)rj * DDIM + lane * 4);
        acc.x += zv.x; acc.y += zv.y; acc.z += zv.z; acc.w += zv.w;
        int cn = (j < 63) ? __shfl(c, j + 1) : -1;
        if (cn != cj) {                // wave-uniform branch
            float* p = esum + (size_t)cj * DDIM + lane * 4;
            atomicAdd(p + 0, acc.x);
            atomicAdd(p + 1, acc.y);
            atomicAdd(p + 2, acc.z);
            atomicAdd(p + 3, acc.w);
            acc.x = 0.f; acc.y = 0.f; acc.z = 0.f; acc.w = 0.f;
        }
    }
}

// ---------------------------------------------------------------------------
__global__ __launch_bounds__(256)
void k_embed(const float* __restrict__ ea, const float* __restrict__ esum,
             const float* __restrict__ ncs, const float* __restrict__ n_ws,
             float* __restrict__ out_nea, float* __restrict__ out_nemb) {
    int k = blockIdx.x;
    int d = threadIdx.x;
    size_t off = (size_t)k * DDIM + d;
    float nea = ea[off] * 0.99f + 0.01f * esum[off];
    out_nea[off] = nea;
    float cs = (ncs[k] + 1e-6f) / (n_ws[0] + 0.001024f);   // (ncs+eps)/(n+K*eps)
    out_nemb[off] = nea / cs;
}

// ---------------------------------------------------------------------------
extern "C" void kernel_launch(void* const* d_in, const int* in_sizes, int n_in,
                              void* d_out, int out_size, void* d_ws, size_t ws_size,
                              hipStream_t stream) {
    const float* z   = (const float*)d_in[0];
    const float* emb = (const float*)d_in[1];
    const float* cs  = (const float*)d_in[2];
    const float* ea  = (const float*)d_in[3];
    float* out = (float*)d_out;
    float* ws  = (float*)d_ws;

    float* esum    = ws + W_ESUM;
    int*   cnts    = (int*)(ws + W_CNT);
    float* enorm   = ws + W_ENORM;
    float* lossp   = ws + W_LOSSP;
    int*   curs    = (int*)(ws + W_CUR);
    float* wn      = ws + W_N;
    int*   widx    = (int*)(ws + W_IDX);
    int*   rsorted = (int*)(ws + W_SORT);

    // packed-B fp16 scratch in dead O_NEA output region (16B-aligned;
    // k_embed, the only writer of that region, runs last). 1MB.
    half_t* Bp = (half_t*)(out + O_NEA + 3);   // 524288 halfs

    hipMemsetAsync(ws, 0, (size_t)(262144 + 1024) * sizeof(float), stream);
    k_prep2  <<<64, 256, 0, stream>>>(emb, enorm, Bp);
    k_argmin <<<NBLK, 512, 0, stream>>>(z, Bp, enorm, emb,
                                        widx, out + O_IDX, out + O_ZQ, lossp, cnts);
    k_scan   <<<1, 256, 0, stream>>>(cs, cnts, lossp, out + O_NCS, curs,
                                     wn, out + O_LOSS);
    k_rank   <<<N_ROWS / 256, 256, 0, stream>>>(widx, curs, rsorted);
    k_esum2  <<<256, 128, 0, stream>>>(z, rsorted, widx, esum);
    k_embed  <<<KCODES, 256, 0, stream>>>(ea, esum, out + O_NCS, wn,
                                          out + O_NEA, out + O_NEMB);
}

// Round 2
// 293.319 us; speedup vs baseline: 1.9220x; 1.9220x over previous
//
#include <hip/hip_runtime.h>

// Problem constants
#define N_ROWS   32768      // 64*512 flattened z rows
#define KCODES   1024
#define DDIM     256
#define RPB      64         // rows per argmin block: As=64KB -> 2 blocks/CU
#define NBLK     512        // 32768/64

// d_out float offsets (outputs concatenated in reference return order)
#define O_ZQ     0                    // 8388608
#define O_LOSS   8388608              // 1
#define O_IDX    8388609              // 32768
#define O_NCS    8421377              // 1024
#define O_NEA    8422401              // 262144
#define O_NEMB   8684545              // 262144

// workspace float offsets
#define W_ESUM   0                    // 262144 (memset, together with CNT)
#define W_CNT    262144               // 1024 ints (memset)
#define W_ENORM  263168               // 1024
#define W_LOSSP  264192               // 512
#define W_CUR    264704               // 1024 ints
#define W_N      265728               // 1
#define W_IDX    265792               // 32768 ints
#define W_SORT   298560               // 32768 ints

typedef _Float16 half_t;
typedef __attribute__((ext_vector_type(8))) _Float16 half8;
typedef __attribute__((ext_vector_type(4))) float floatx4;

// ---------------------------------------------------------------------------
// Pack B into MFMA-native fragment order + compute ||e||^2.
// Bp[ct][pk][lane][8]: ct = 16-code tile (64 tiles), pk = packed k-step
// (16 = seg0 hi + seg1 lo; phase 16..23 reuses pk 0..7 -> 1MB total),
// lane: col=lane&15 (code), k = (lane>>4)*8 + j.
__global__ __launch_bounds__(256)
void k_prep2(const float* __restrict__ emb, float* __restrict__ enorm,
             half_t* __restrict__ Bp) {
    __shared__ half_t hi[16 * 256];
    __shared__ half_t lo[16 * 256];
    __shared__ float  ssum[256];
    const int ct  = blockIdx.x;       // 16-code tile
    const int tid = threadIdx.x;
    const int c16 = tid >> 4;         // code within tile
    const int dp  = tid & 15;         // 16-dim part

    float ss = 0.f;
    #pragma unroll
    for (int i = 0; i < 4; ++i) {
        float4 v = *(const float4*)(emb + (size_t)(ct * 16 + c16) * DDIM + dp * 16 + i * 4);
        ss += v.x * v.x + v.y * v.y + v.z * v.z + v.w * v.w;
        #pragma unroll
        for (int q = 0; q < 4; ++q) {
            float f = (&v.x)[q];
            half_t h = (half_t)f;
            hi[c16 * 256 + dp * 16 + i * 4 + q] = h;
            lo[c16 * 256 + dp * 16 + i * 4 + q] = (half_t)(f - (float)h);
        }
    }
    ssum[tid] = ss;
    __syncthreads();
    if (tid < 16) {
        float s = 0.f;
        #pragma unroll
        for (int i = 0; i < 16; ++i) s += ssum[tid * 16 + i];
        enorm[ct * 16 + tid] = s;
    }

    // write phase: 16 packed steps x 64 lanes x 8 halfs
    #pragma unroll
    for (int i = 0; i < 4; ++i) {
        int f    = tid + i * 256;     // 0..1023
        int ks   = f >> 6;            // 0..15
        int lane = f & 63;
        int cc   = lane & 15;
        int seg  = ks >> 3;           // 0:hi 1:lo
        int ko   = (ks & 7) * 32 + (lane >> 4) * 8;
        const half_t* src = (seg == 1) ? lo : hi;
        half8 v = *(const half8*)(src + cc * 256 + ko);
        *(half8*)(Bp + ((size_t)(ct * 16 + ks) * 64 + lane) * 8) = v;
    }
}

// ---------------------------------------------------------------------------
// MFMA argmin. dist(r,c)=||e||^2-2 z.e; fp16 hi/lo K-concat (K'=768):
// phase c=0: z_hi.e_hi, c=1: z_hi.e_lo, c=2: z_lo.e_hi (B reuses pk 0..7).
// R9: 512 threads = 8 waves/block; per-wave tile 32 rows x 256 codes
// (acc[2][4]=32 VGPR, ping-pong B prefetch=32 VGPR, working set ~110).
// PLAIN __launch_bounds__(512) — NO min-waves arg, EVER: R5/R7/R8 all
// proved the second arg is a MINIMUM and the allocator's occupancy
// heuristic overshoots it (R8: chose 8 waves/EU -> 64-VGPR cap -> 1.2GB
// scratch spill, 441us). Unconstrained, the allocator is spill-averse;
// if it lands <=128 VGPR we get 2 blocks/CU x 8 waves = 4 waves/SIMD.
__global__ __launch_bounds__(512)
void k_argmin(const float* __restrict__ z, const half_t* __restrict__ Bp,
              const float* __restrict__ enorm, const float* __restrict__ embf,
              int* __restrict__ out_idx, float* __restrict__ out_idx_f,
              float* __restrict__ out_zq, float* __restrict__ lossp,
              int* __restrict__ counts_i) {
    __shared__ __align__(16) half_t As[RPB * 512];   // 64 KB

    const int tid  = threadIdx.x;
    const int w    = tid >> 6;        // 0..7
    const int lane = tid & 63;
    const int tx   = lane & 15;
    const int quad = lane >> 4;
    const int rh   = w >> 2;          // row half: 0 -> rows 0..31, 1 -> 32..63
    const int cq   = w & 3;           // code quarter: codes [cq*256, cq*256+256)
    const int rbase = blockIdx.x * RPB;

    // ---- stage A: read z fp32, split hi/lo in-register, swizzled LDS store
    #pragma unroll
    for (int it = 0; it < 4; ++it) {
        int f   = tid + it * 512;
        int row = f >> 5;             // 0..63
        int g   = f & 31;
        const float* zp = z + (size_t)(rbase + row) * DDIM + g * 8;
        float4 v0 = *(const float4*)zp;
        float4 v1 = *(const float4*)(zp + 4);
        half8 hi, lo;
        hi[0] = (half_t)v0.x; lo[0] = (half_t)(v0.x - (float)hi[0]);
        hi[1] = (half_t)v0.y; lo[1] = (half_t)(v0.y - (float)hi[1]);
        hi[2] = (half_t)v0.z; lo[2] = (half_t)(v0.z - (float)hi[2]);
        hi[3] = (half_t)v0.w; lo[3] = (half_t)(v0.w - (float)hi[3]);
        hi[4] = (half_t)v1.x; lo[4] = (half_t)(v1.x - (float)hi[4]);
        hi[5] = (half_t)v1.y; lo[5] = (half_t)(v1.y - (float)hi[5]);
        hi[6] = (half_t)v1.z; lo[6] = (half_t)(v1.z - (float)hi[6]);
        hi[7] = (half_t)v1.w; lo[7] = (half_t)(v1.w - (float)hi[7]);
        int sw = row & 7;
        *(half8*)(&As[row * 512 + ((g ^ sw)) * 8])        = hi;  // k8 = g
        *(half8*)(&As[row * 512 + (((32 + g) ^ sw)) * 8]) = lo;  // k8 = 32+g
    }
    __syncthreads();                  // the ONLY main-loop barrier

    floatx4 zero4 = {0.f, 0.f, 0.f, 0.f};
    float bd[2][4];
    int   bi[2][4];
    #pragma unroll
    for (int mt = 0; mt < 2; ++mt)
        #pragma unroll
        for (int r = 0; r < 4; ++r) { bd[mt][r] = 3.402823466e38f; bi[mt][r] = 0; }

    for (int g4 = 0; g4 < 4; ++g4) {
        const int cb = cq * 256 + g4 * 64;
        // wave's 4 tiles this group: global ct = cq*16 + g4*4 + ns
        // Bp layout: ct stride 8192 halfs, pk stride 512, lane stride 8
        const half_t* Bg = Bp + (size_t)(cq * 16 + g4 * 4) * 8192 + lane * 8;

        floatx4 acc[2][4];
        #pragma unroll
        for (int mt = 0; mt < 2; ++mt)
            #pragma unroll
            for (int ns = 0; ns < 4; ++ns) acc[mt][ns] = zero4;

        half8 B0[4], B1[4];
        // phase P -> packed index (phases 16..23 reuse 0..7, L2-warm)
        #define LOADB(P, BUF)                                                  \
            { const int pk_ = ((P) < 16) ? (P) : ((P) - 16);                   \
              _Pragma("unroll")                                                \
              for (int ns = 0; ns < 4; ++ns)                                   \
                  BUF[ns] = *(const half8*)(Bg + (size_t)(ns * 16 + pk_) * 512); }
        LOADB(0, B0);
        LOADB(1, B1);

        #pragma unroll
        for (int ks = 0; ks < 24; ++ks) {
            const int c   = ks >> 3;
            const int k8b = (c == 2 ? 32 : 0) + (ks & 7) * 4;
            half8 a[2];
            #pragma unroll
            for (int mt = 0; mt < 2; ++mt) {
                int row = rh * 32 + mt * 16 + tx;
                a[mt] = *(half8*)(&As[row * 512 + ((k8b + quad) ^ (row & 7)) * 8]);
            }
            #pragma unroll
            for (int mt = 0; mt < 2; ++mt)
                #pragma unroll
                for (int ns = 0; ns < 4; ++ns) {
                    const half8& bb = (ks & 1) ? B1[ns] : B0[ns];
                    acc[mt][ns] = __builtin_amdgcn_mfma_f32_16x16x32_f16(a[mt], bb, acc[mt][ns], 0, 0, 0);
                }
            // ping-pong prefetch: refill the buffer just consumed (WAR on
            // regs keeps ordering); arrives during step ks+1, used at ks+2.
            if (ks + 2 < 24) {
                if (ks & 1) { LOADB(ks + 2, B1); }
                else        { LOADB(ks + 2, B0); }
            }
        }
        #undef LOADB

        // fold group into running argmin (codes ascending; strict <, min-index)
        #pragma unroll
        for (int ns = 0; ns < 4; ++ns) {
            float en = enorm[cb + ns * 16 + tx];
            int   cc = cb + ns * 16 + tx;
            #pragma unroll
            for (int mt = 0; mt < 2; ++mt)
                #pragma unroll
                for (int r = 0; r < 4; ++r) {
                    float d = fmaf(-2.f, acc[mt][ns][r], en);
                    if (d < bd[mt][r]) { bd[mt][r] = d; bi[mt][r] = cc; }
                }
        }
    }

    // reduce across 16 tx lanes (same row, different codes); ties -> min index
    #pragma unroll
    for (int mt = 0; mt < 2; ++mt)
        #pragma unroll
        for (int r = 0; r < 4; ++r) {
            float d = bd[mt][r];
            int   b = bi[mt][r];
            #pragma unroll
            for (int off = 8; off > 0; off >>= 1) {
                float od = __shfl_xor(d, off);
                int   ob = __shfl_xor(b, off);
                if (od < d || (od == d && ob < b)) { d = od; b = ob; }
            }
            bd[mt][r] = d; bi[mt][r] = b;
        }

    // cross-wave reduce via LDS (reuse As): per row, 4 code-quarter candidates
    __syncthreads();
    float* sd   = (float*)As;          // [64 rows][4 quarters]
    int*   si   = ((int*)As) + 256;
    int*   sidx = ((int*)As) + 512;    // final idx per row
    if (tx == 0) {
        #pragma unroll
        for (int mt = 0; mt < 2; ++mt)
            #pragma unroll
            for (int r = 0; r < 4; ++r) {
                int row = rh * 32 + mt * 16 + quad * 4 + r;  // C-layout: row = quad*4+reg
                sd[row * 4 + cq] = bd[mt][r];
                si[row * 4 + cq] = bi[mt][r];
            }
    }
    __syncthreads();
    if (tid < RPB) {
        int row = tid;
        float d = sd[row * 4];
        int   b = si[row * 4];
        #pragma unroll
        for (int ww = 1; ww < 4; ++ww) {
            float od = sd[row * 4 + ww];
            int   ob = si[row * 4 + ww];
            if (od < d || (od == d && ob < b)) { d = od; b = ob; }
        }
        sidx[row] = b;
        out_idx[rbase + row]   = b;
        out_idx_f[rbase + row] = (float)b;
        atomicAdd(&counts_i[b], 1);
    }
    __syncthreads();

    // ---- fused z_q epilogue: z_q_st write + commitment-loss partial
    float l = 0.f;
    #pragma unroll
    for (int u = 0; u < 8; ++u) {
        int gi  = tid + u * 512;       // 0..4095 float4s = 64 rows x 64
        int row = gi >> 6;
        int c4  = gi & 63;
        int k   = sidx[row];           // wave-uniform
        float4 zv = *(const float4*)(z    + (size_t)(rbase + row) * DDIM + c4 * 4);
        float4 ev = *(const float4*)(embf + (size_t)k * DDIM + c4 * 4);
        float dx = ev.x - zv.x, dy = ev.y - zv.y, dz = ev.z - zv.z, dw = ev.w - zv.w;
        float4 o = { zv.x + dx, zv.y + dy, zv.z + dz, zv.w + dw };  // z + (z_q - z)
        *(float4*)(out_zq + (size_t)(rbase + row) * DDIM + c4 * 4) = o;
        l += dx * dx + dy * dy + dz * dz + dw * dw;
    }
    #pragma unroll
    for (int off = 32; off > 0; off >>= 1) l += __shfl_down(l, off);
    __shared__ float ls[8];
    if (lane == 0) ls[w] = l;
    __syncthreads();
    if (tid == 0) {
        float s = 0.f;
        #pragma unroll
        for (int i = 0; i < 8; ++i) s += ls[i];
        lossp[blockIdx.x] = s;
    }
}

// ---------------------------------------------------------------------------
// Single block: prefix-sum counts -> cursors; ncs/n/loss finalization.
__global__ __launch_bounds__(256)
void k_scan(const float* __restrict__ cs_in, const int* __restrict__ counts_i,
            const float* __restrict__ lossp, float* __restrict__ out_ncs,
            int* __restrict__ cursors,
            float* __restrict__ n_out, float* __restrict__ loss_out) {
    const int tid = threadIdx.x;
    __shared__ int ps[256];
    int c[4]; int pt = 0;
    #pragma unroll
    for (int i = 0; i < 4; ++i) { c[i] = counts_i[tid * 4 + i]; pt += c[i]; }
    ps[tid] = pt;
    __syncthreads();
    for (int s = 1; s < 256; s <<= 1) {
        int v = (tid >= s) ? ps[tid - s] : 0;
        __syncthreads();
        ps[tid] += v;
        __syncthreads();
    }
    int o = ps[tid] - pt;              // exclusive base for this thread's 4 bins
    float v = 0.f;
    #pragma unroll
    for (int i = 0; i < 4; ++i) {
        cursors[tid * 4 + i] = o;
        o += c[i];
        float nc = cs_in[tid * 4 + i] * 0.99f + 0.01f * (float)c[i];
        out_ncs[tid * 4 + i] = nc;
        v += nc;
    }
    float l = 0.f;
    for (int i = tid; i < NBLK; i += 256) l += lossp[i];
    #pragma unroll
    for (int off = 32; off > 0; off >>= 1) {
        v += __shfl_down(v, off);
        l += __shfl_down(l, off);
    }
    __shared__ float sv[4], sl[4];
    if ((tid & 63) == 0) { sv[tid >> 6] = v; sl[tid >> 6] = l; }
    __syncthreads();
    if (tid == 0) {
        n_out[0]    = sv[0] + sv[1] + sv[2] + sv[3];
        loss_out[0] = 0.25f * ((sl[0] + sl[1] + sl[2] + sl[3]) / 8388608.0f);
    }
}

// ---------------------------------------------------------------------------
// Scatter row ids into per-code contiguous lists (counting sort, phase 2).
__global__ __launch_bounds__(256)
void k_rank(const int* __restrict__ idx, int* __restrict__ cursors,
            int* __restrict__ rows_sorted) {
    int r = blockIdx.x * 256 + threadIdx.x;
    int k = idx[r];
    int pos = atomicAdd(&cursors[k], 1);
    rows_sorted[pos] = r;
}

// ---------------------------------------------------------------------------
// Skew-proof segment-sum: each wave owns exactly 64 sorted positions,
// accumulates equal-code runs in registers, flushes runs via fp32 atomics.
__global__ __launch_bounds__(128)
void k_esum2(const float* __restrict__ z, const int* __restrict__ rows_sorted,
             const int* __restrict__ idx, float* __restrict__ esum) {
    const int tid  = threadIdx.x;
    const int w    = tid >> 6;
    const int lane = tid & 63;
    const int base = (blockIdx.x * 2 + w) * 64;   // 256 blocks x 2 waves

    int r = rows_sorted[base + lane];
    int c = idx[r];
    float4 acc = {0.f, 0.f, 0.f, 0.f};
    #pragma unroll 8
    for (int j = 0; j < 64; ++j) {
        int rj = __shfl(r, j);
        int cj = __shfl(c, j);
        float4 zv = *(const float4*)(z + (size_t)rj * DDIM + lane * 4);
        acc.x += zv.x; acc.y += zv.y; acc.z += zv.z; acc.w += zv.w;
        int cn = (j < 63) ? __shfl(c, j + 1) : -1;
        if (cn != cj) {                // wave-uniform branch
            float* p = esum + (size_t)cj * DDIM + lane * 4;
            atomicAdd(p + 0, acc.x);
            atomicAdd(p + 1, acc.y);
            atomicAdd(p + 2, acc.z);
            atomicAdd(p + 3, acc.w);
            acc.x = 0.f; acc.y = 0.f; acc.z = 0.f; acc.w = 0.f;
        }
    }
}

// ---------------------------------------------------------------------------
__global__ __launch_bounds__(256)
void k_embed(const float* __restrict__ ea, const float* __restrict__ esum,
             const float* __restrict__ ncs, const float* __restrict__ n_ws,
             float* __restrict__ out_nea, float* __restrict__ out_nemb) {
    int k = blockIdx.x;
    int d = threadIdx.x;
    size_t off = (size_t)k * DDIM + d;
    float nea = ea[off] * 0.99f + 0.01f * esum[off];
    out_nea[off] = nea;
    float cs = (ncs[k] + 1e-6f) / (n_ws[0] + 0.001024f);   // (ncs+eps)/(n+K*eps)
    out_nemb[off] = nea / cs;
}

// ---------------------------------------------------------------------------
extern "C" void kernel_launch(void* const* d_in, const int* in_sizes, int n_in,
                              void* d_out, int out_size, void* d_ws, size_t ws_size,
                              hipStream_t stream) {
    const float* z   = (const float*)d_in[0];
    const float* emb = (const float*)d_in[1];
    const float* cs  = (const float*)d_in[2];
    const float* ea  = (const float*)d_in[3];
    float* out = (float*)d_out;
    float* ws  = (float*)d_ws;

    float* esum    = ws + W_ESUM;
    int*   cnts    = (int*)(ws + W_CNT);
    float* enorm   = ws + W_ENORM;
    float* lossp   = ws + W_LOSSP;
    int*   curs    = (int*)(ws + W_CUR);
    float* wn      = ws + W_N;
    int*   widx    = (int*)(ws + W_IDX);
    int*   rsorted = (int*)(ws + W_SORT);

    // packed-B fp16 scratch in dead O_NEA output region (16B-aligned;
    // k_embed, the only writer of that region, runs last). 1MB.
    half_t* Bp = (half_t*)(out + O_NEA + 3);   // 524288 halfs

    hipMemsetAsync(ws, 0, (size_t)(262144 + 1024) * sizeof(float), stream);
    k_prep2  <<<64, 256, 0, stream>>>(emb, enorm, Bp);
    k_argmin <<<NBLK, 512, 0, stream>>>(z, Bp, enorm, emb,
                                        widx, out + O_IDX, out + O_ZQ, lossp, cnts);
    k_scan   <<<1, 256, 0, stream>>>(cs, cnts, lossp, out + O_NCS, curs,
                                     wn, out + O_LOSS);
    k_rank   <<<N_ROWS / 256, 256, 0, stream>>>(widx, curs, rsorted);
    k_esum2  <<<256, 128, 0, stream>>>(z, rsorted, widx, esum);
    k_embed  <<<KCODES, 256, 0, stream>>>(ea, esum, out + O_NCS, wn,
                                          out + O_NEA, out + O_NEMB);
}

// Round 3
// 202.055 us; speedup vs baseline: 2.7901x; 1.4517x over previous
//
#include <hip/hip_runtime.h>

// Problem constants
#define N_ROWS   32768      // 64*512 flattened z rows
#define KCODES   1024
#define DDIM     256
#define RPB      64         // rows per argmin block: As=64KB -> 2 blocks/CU
#define NBLK     512        // 32768/64

// d_out float offsets (outputs concatenated in reference return order)
#define O_ZQ     0                    // 8388608
#define O_LOSS   8388608              // 1
#define O_IDX    8388609              // 32768
#define O_NCS    8421377              // 1024
#define O_NEA    8422401              // 262144
#define O_NEMB   8684545              // 262144

// workspace float offsets
#define W_ESUM   0                    // 262144 (zeroed in k_prep2, with CNT)
#define W_CNT    262144               // 1024 ints (zeroed in k_prep2)
#define W_ENORM  263168               // 1024
#define W_LOSSP  264192               // 512
#define W_CUR    264704               // 1024 ints
#define W_N      265728               // 1
#define W_IDX    265792               // 32768 ints
#define W_SORT   298560               // 32768 ints

typedef _Float16 half_t;
typedef __attribute__((ext_vector_type(8))) _Float16 half8;
typedef __attribute__((ext_vector_type(4))) float floatx4;

// ---------------------------------------------------------------------------
// Pack B into MFMA-native fragment order + compute ||e||^2.
// R3 layout (compact-addressing): Bp[g16][pk][ns][lane][8]:
//   g16 = cq*4+g4 (wave-group, 16), pk = packed k-step (16: hi + lo-low-half;
//   phases 16..23 reuse pk 0..7), ns = 16-code subtile (4), lane as before
//   (col=lane&15, k=(lane>>4)*8+j). A wave-step's 4 ns loads now span one
//   contiguous 4KB window -> single address reg + imm offsets in k_argmin.
// Also zeroes esum+cnts workspace (absorbs the old hipMemsetAsync dispatch).
__global__ __launch_bounds__(256)
void k_prep2(const float* __restrict__ emb, float* __restrict__ enorm,
             half_t* __restrict__ Bp, float* __restrict__ zero_ws) {
    __shared__ half_t hi[16 * 256];
    __shared__ half_t lo[16 * 256];
    __shared__ float  ssum[256];
    const int ct  = blockIdx.x;       // 16-code tile
    const int tid = threadIdx.x;
    const int c16 = tid >> 4;         // code within tile
    const int dp  = tid & 15;         // 16-dim part

    // zero esum (262144 f) + cnts (1024 i) = 65792 float4s across 16384 thr
    {
        float4 z4 = {0.f, 0.f, 0.f, 0.f};
        float4* wsf4 = (float4*)zero_ws;
        int t = ct * 256 + tid;
        #pragma unroll
        for (int i = 0; i < 4; ++i) wsf4[t + i * 16384] = z4;
        if (t < 256) wsf4[65536 + t] = z4;
    }

    float ss = 0.f;
    #pragma unroll
    for (int i = 0; i < 4; ++i) {
        float4 v = *(const float4*)(emb + (size_t)(ct * 16 + c16) * DDIM + dp * 16 + i * 4);
        ss += v.x * v.x + v.y * v.y + v.z * v.z + v.w * v.w;
        #pragma unroll
        for (int q = 0; q < 4; ++q) {
            float f = (&v.x)[q];
            half_t h = (half_t)f;
            hi[c16 * 256 + dp * 16 + i * 4 + q] = h;
            lo[c16 * 256 + dp * 16 + i * 4 + q] = (half_t)(f - (float)h);
        }
    }
    ssum[tid] = ss;
    __syncthreads();
    if (tid < 16) {
        float s = 0.f;
        #pragma unroll
        for (int i = 0; i < 16; ++i) s += ssum[tid * 16 + i];
        enorm[ct * 16 + tid] = s;
    }

    // write phase: 16 packed steps x 64 lanes x 8 halfs, new layout
    const int g16 = ((ct >> 4) << 2) | ((ct >> 2) & 3);
    const int ns  = ct & 3;
    #pragma unroll
    for (int i = 0; i < 4; ++i) {
        int f    = tid + i * 256;     // 0..1023
        int ks   = f >> 6;            // pk 0..15
        int lane = f & 63;
        int cc   = lane & 15;
        int seg  = ks >> 3;           // 0:hi 1:lo
        int ko   = (ks & 7) * 32 + (lane >> 4) * 8;
        const half_t* src = (seg == 1) ? lo : hi;
        half8 v = *(const half8*)(src + cc * 256 + ko);
        // offset = (((g16*16 + pk)*4 + ns)*64 + lane)*8 halfs
        *(half8*)(Bp + (((size_t)(g16 * 16 + ks) * 4 + ns) * 64 + lane) * 8) = v;
    }
}

// ---------------------------------------------------------------------------
// MFMA argmin. dist(r,c)=||e||^2-2 z.e; fp16 hi/lo K-concat (K'=768):
// phase c=0: z_hi.e_hi, c=1: z_hi.e_lo, c=2: z_lo.e_hi (B reuses pk 0..7).
// R3: 512 thr = 8 waves; wave tile 32 rows x 256 codes (acc[2][4]=32 VGPR,
// ping-pong B=32). K-loop ROLLED (#pragma unroll 2 keeps ping-pong parity
// static) + compact Bp layout: 4 ns loads share one address reg via imm
// offsets -> no per-step address materialization (R2's spill source:
// FETCH/WRITE +280MB at VGPR=128). Target: fit 128 VGPR spill-free ->
// 2 blocks/CU x 8 waves = 4 waves/SIMD.
// PLAIN __launch_bounds__(512) — NO min-waves arg, EVER (R5/R7/R8: the 2nd
// arg is a MINIMUM; allocator overshoots -> 64-VGPR cap -> 1.2GB spill).
__global__ __launch_bounds__(512)
void k_argmin(const float* __restrict__ z, const half_t* __restrict__ Bp,
              const float* __restrict__ enorm, const float* __restrict__ embf,
              int* __restrict__ out_idx, float* __restrict__ out_idx_f,
              float* __restrict__ out_zq, float* __restrict__ lossp,
              int* __restrict__ counts_i) {
    __shared__ __align__(16) half_t As[RPB * 512];   // 64 KB

    const int tid  = threadIdx.x;
    const int w    = tid >> 6;        // 0..7
    const int lane = tid & 63;
    const int tx   = lane & 15;
    const int quad = lane >> 4;
    const int rh   = w >> 2;          // row half: 0 -> rows 0..31, 1 -> 32..63
    const int cq   = w & 3;           // code quarter: codes [cq*256, cq*256+256)
    const int rbase = blockIdx.x * RPB;

    // ---- stage A: read z fp32, split hi/lo in-register, swizzled LDS store
    #pragma unroll
    for (int it = 0; it < 4; ++it) {
        int f   = tid + it * 512;
        int row = f >> 5;             // 0..63
        int g   = f & 31;
        const float* zp = z + (size_t)(rbase + row) * DDIM + g * 8;
        float4 v0 = *(const float4*)zp;
        float4 v1 = *(const float4*)(zp + 4);
        half8 hi, lo;
        hi[0] = (half_t)v0.x; lo[0] = (half_t)(v0.x - (float)hi[0]);
        hi[1] = (half_t)v0.y; lo[1] = (half_t)(v0.y - (float)hi[1]);
        hi[2] = (half_t)v0.z; lo[2] = (half_t)(v0.z - (float)hi[2]);
        hi[3] = (half_t)v0.w; lo[3] = (half_t)(v0.w - (float)hi[3]);
        hi[4] = (half_t)v1.x; lo[4] = (half_t)(v1.x - (float)hi[4]);
        hi[5] = (half_t)v1.y; lo[5] = (half_t)(v1.y - (float)hi[5]);
        hi[6] = (half_t)v1.z; lo[6] = (half_t)(v1.z - (float)hi[6]);
        hi[7] = (half_t)v1.w; lo[7] = (half_t)(v1.w - (float)hi[7]);
        int sw = row & 7;
        *(half8*)(&As[row * 512 + ((g ^ sw)) * 8])        = hi;  // k8 = g
        *(half8*)(&As[row * 512 + (((32 + g) ^ sw)) * 8]) = lo;  // k8 = 32+g
    }
    __syncthreads();                  // the ONLY main-loop barrier

    floatx4 zero4 = {0.f, 0.f, 0.f, 0.f};
    float bd[2][4];
    int   bi[2][4];
    #pragma unroll
    for (int mt = 0; mt < 2; ++mt)
        #pragma unroll
        for (int r = 0; r < 4; ++r) { bd[mt][r] = 3.402823466e38f; bi[mt][r] = 0; }

    for (int g4 = 0; g4 < 4; ++g4) {
        const int cb = cq * 256 + g4 * 64;
        // compact layout: g16 = cq*4+g4; Bg + pk*2048 + ns*512 (halfs),
        // ns window = 4KB -> imm offsets from one per-step address.
        const half_t* Bg = Bp + (size_t)(cq * 4 + g4) * 32768 + (size_t)lane * 8;

        floatx4 acc[2][4];
        #pragma unroll
        for (int mt = 0; mt < 2; ++mt)
            #pragma unroll
            for (int ns = 0; ns < 4; ++ns) acc[mt][ns] = zero4;

        half8 B0[4], B1[4];
        #define LOADB(PK, BUF)                                                 \
            { const half_t* bp_ = Bg + (PK) * 2048;                            \
              _Pragma("unroll")                                                \
              for (int ns = 0; ns < 4; ++ns)                                   \
                  BUF[ns] = *(const half8*)(bp_ + ns * 512); }
        #define MFMA_BLK(BUF)                                                  \
            _Pragma("unroll")                                                  \
            for (int mt = 0; mt < 2; ++mt)                                     \
                _Pragma("unroll")                                              \
                for (int ns = 0; ns < 4; ++ns)                                 \
                    acc[mt][ns] = __builtin_amdgcn_mfma_f32_16x16x32_f16(      \
                        a[mt], BUF[ns], acc[mt][ns], 0, 0, 0);

        LOADB(0, B0);
        LOADB(1, B1);

        #pragma unroll 2
        for (int ks = 0; ks < 24; ++ks) {
            // phases 0..15 read pk=ks; 16..23 reuse pk 0..7 (k8 base 32 = z_lo)
            const int k8b = ((ks & 16) << 1) + (ks & 7) * 4;
            half8 a[2];
            #pragma unroll
            for (int mt = 0; mt < 2; ++mt) {
                int row = rh * 32 + mt * 16 + tx;
                a[mt] = *(half8*)(&As[row * 512 + ((k8b + quad) ^ (row & 7)) * 8]);
            }
            if (ks & 1) { MFMA_BLK(B1) } else { MFMA_BLK(B0) }
            // ping-pong prefetch: refill buffer just consumed; (ks+2)&15
            // implements the pk 16..23 -> 0..7 reuse.
            if (ks + 2 < 24) {
                const int pkp = (ks + 2) & 15;
                if (ks & 1) { LOADB(pkp, B1); } else { LOADB(pkp, B0); }
            }
        }
        #undef LOADB
        #undef MFMA_BLK

        // fold group into running argmin (codes ascending; strict <, min-index)
        #pragma unroll
        for (int ns = 0; ns < 4; ++ns) {
            float en = enorm[cb + ns * 16 + tx];
            int   cc = cb + ns * 16 + tx;
            #pragma unroll
            for (int mt = 0; mt < 2; ++mt)
                #pragma unroll
                for (int r = 0; r < 4; ++r) {
                    float d = fmaf(-2.f, acc[mt][ns][r], en);
                    if (d < bd[mt][r]) { bd[mt][r] = d; bi[mt][r] = cc; }
                }
        }
    }

    // reduce across 16 tx lanes (same row, different codes); ties -> min index
    #pragma unroll
    for (int mt = 0; mt < 2; ++mt)
        #pragma unroll
        for (int r = 0; r < 4; ++r) {
            float d = bd[mt][r];
            int   b = bi[mt][r];
            #pragma unroll
            for (int off = 8; off > 0; off >>= 1) {
                float od = __shfl_xor(d, off);
                int   ob = __shfl_xor(b, off);
                if (od < d || (od == d && ob < b)) { d = od; b = ob; }
            }
            bd[mt][r] = d; bi[mt][r] = b;
        }

    // cross-wave reduce via LDS (reuse As): per row, 4 code-quarter candidates
    __syncthreads();
    float* sd   = (float*)As;          // [64 rows][4 quarters]
    int*   si   = ((int*)As) + 256;
    int*   sidx = ((int*)As) + 512;    // final idx per row
    if (tx == 0) {
        #pragma unroll
        for (int mt = 0; mt < 2; ++mt)
            #pragma unroll
            for (int r = 0; r < 4; ++r) {
                int row = rh * 32 + mt * 16 + quad * 4 + r;  // C-layout: row = quad*4+reg
                sd[row * 4 + cq] = bd[mt][r];
                si[row * 4 + cq] = bi[mt][r];
            }
    }
    __syncthreads();
    if (tid < RPB) {
        int row = tid;
        float d = sd[row * 4];
        int   b = si[row * 4];
        #pragma unroll
        for (int ww = 1; ww < 4; ++ww) {
            float od = sd[row * 4 + ww];
            int   ob = si[row * 4 + ww];
            if (od < d || (od == d && ob < b)) { d = od; b = ob; }
        }
        sidx[row] = b;
        out_idx[rbase + row]   = b;
        out_idx_f[rbase + row] = (float)b;
        atomicAdd(&counts_i[b], 1);
    }
    __syncthreads();

    // ---- fused z_q epilogue: z_q_st write + commitment-loss partial
    float l = 0.f;
    #pragma unroll
    for (int u = 0; u < 8; ++u) {
        int gi  = tid + u * 512;       // 0..4095 float4s = 64 rows x 64
        int row = gi >> 6;
        int c4  = gi & 63;
        int k   = sidx[row];           // wave-uniform
        float4 zv = *(const float4*)(z    + (size_t)(rbase + row) * DDIM + c4 * 4);
        float4 ev = *(const float4*)(embf + (size_t)k * DDIM + c4 * 4);
        float dx = ev.x - zv.x, dy = ev.y - zv.y, dz = ev.z - zv.z, dw = ev.w - zv.w;
        float4 o = { zv.x + dx, zv.y + dy, zv.z + dz, zv.w + dw };  // z + (z_q - z)
        *(float4*)(out_zq + (size_t)(rbase + row) * DDIM + c4 * 4) = o;
        l += dx * dx + dy * dy + dz * dz + dw * dw;
    }
    #pragma unroll
    for (int off = 32; off > 0; off >>= 1) l += __shfl_down(l, off);
    __shared__ float ls[8];
    if (lane == 0) ls[w] = l;
    __syncthreads();
    if (tid == 0) {
        float s = 0.f;
        #pragma unroll
        for (int i = 0; i < 8; ++i) s += ls[i];
        lossp[blockIdx.x] = s;
    }
}

// ---------------------------------------------------------------------------
// Single block: prefix-sum counts -> cursors; ncs/n/loss finalization.
__global__ __launch_bounds__(256)
void k_scan(const float* __restrict__ cs_in, const int* __restrict__ counts_i,
            const float* __restrict__ lossp, float* __restrict__ out_ncs,
            int* __restrict__ cursors,
            float* __restrict__ n_out, float* __restrict__ loss_out) {
    const int tid = threadIdx.x;
    __shared__ int ps[256];
    int c[4]; int pt = 0;
    #pragma unroll
    for (int i = 0; i < 4; ++i) { c[i] = counts_i[tid * 4 + i]; pt += c[i]; }
    ps[tid] = pt;
    __syncthreads();
    for (int s = 1; s < 256; s <<= 1) {
        int v = (tid >= s) ? ps[tid - s] : 0;
        __syncthreads();
        ps[tid] += v;
        __syncthreads();
    }
    int o = ps[tid] - pt;              // exclusive base for this thread's 4 bins
    float v = 0.f;
    #pragma unroll
    for (int i = 0; i < 4; ++i) {
        cursors[tid * 4 + i] = o;
        o += c[i];
        float nc = cs_in[tid * 4 + i] * 0.99f + 0.01f * (float)c[i];
        out_ncs[tid * 4 + i] = nc;
        v += nc;
    }
    float l = 0.f;
    for (int i = tid; i < NBLK; i += 256) l += lossp[i];
    #pragma unroll
    for (int off = 32; off > 0; off >>= 1) {
        v += __shfl_down(v, off);
        l += __shfl_down(l, off);
    }
    __shared__ float sv[4], sl[4];
    if ((tid & 63) == 0) { sv[tid >> 6] = v; sl[tid >> 6] = l; }
    __syncthreads();
    if (tid == 0) {
        n_out[0]    = sv[0] + sv[1] + sv[2] + sv[3];
        loss_out[0] = 0.25f * ((sl[0] + sl[1] + sl[2] + sl[3]) / 8388608.0f);
    }
}

// ---------------------------------------------------------------------------
// Scatter row ids into per-code contiguous lists (counting sort, phase 2).
__global__ __launch_bounds__(256)
void k_rank(const int* __restrict__ idx, int* __restrict__ cursors,
            int* __restrict__ rows_sorted) {
    int r = blockIdx.x * 256 + threadIdx.x;
    int k = idx[r];
    int pos = atomicAdd(&cursors[k], 1);
    rows_sorted[pos] = r;
}

// ---------------------------------------------------------------------------
// Skew-proof segment-sum. R3: 4 waves/block x 32 sorted positions (was
// 2 x 64) -> 1024 wave-tasks, 4 waves/CU, half the serial chain per wave.
// Chunk-boundary runs flush their partials via atomics (correct by
// construction). Lanes 32..63 duplicate lanes 0..31's r/c (avoids OOB;
// broadcasts only read lanes 0..31).
__global__ __launch_bounds__(256)
void k_esum2(const float* __restrict__ z, const int* __restrict__ rows_sorted,
             const int* __restrict__ idx, float* __restrict__ esum) {
    const int tid  = threadIdx.x;
    const int w    = tid >> 6;        // 0..3
    const int lane = tid & 63;
    const int base = (blockIdx.x * 4 + w) * 32;   // 256 blocks x 4 waves x 32

    int r = rows_sorted[base + (lane & 31)];
    int c = idx[r];
    float4 acc = {0.f, 0.f, 0.f, 0.f};
    #pragma unroll 8
    for (int j = 0; j < 32; ++j) {
        int rj = __shfl(r, j);
        int cj = __shfl(c, j);
        float4 zv = *(const float4*)(z + (size_t)rj * DDIM + lane * 4);
        acc.x += zv.x; acc.y += zv.y; acc.z += zv.z; acc.w += zv.w;
        int cn = (j < 31) ? __shfl(c, j + 1) : -1;
        if (cn != cj) {                // wave-uniform branch
            float* p = esum + (size_t)cj * DDIM + lane * 4;
            atomicAdd(p + 0, acc.x);
            atomicAdd(p + 1, acc.y);
            atomicAdd(p + 2, acc.z);
            atomicAdd(p + 3, acc.w);
            acc.x = 0.f; acc.y = 0.f; acc.z = 0.f; acc.w = 0.f;
        }
    }
}

// ---------------------------------------------------------------------------
__global__ __launch_bounds__(256)
void k_embed(const float* __restrict__ ea, const float* __restrict__ esum,
             const float* __restrict__ ncs, const float* __restrict__ n_ws,
             float* __restrict__ out_nea, float* __restrict__ out_nemb) {
    int k = blockIdx.x;
    int d = threadIdx.x;
    size_t off = (size_t)k * DDIM + d;
    float nea = ea[off] * 0.99f + 0.01f * esum[off];
    out_nea[off] = nea;
    float cs = (ncs[k] + 1e-6f) / (n_ws[0] + 0.001024f);   // (ncs+eps)/(n+K*eps)
    out_nemb[off] = nea / cs;
}

// ---------------------------------------------------------------------------
extern "C" void kernel_launch(void* const* d_in, const int* in_sizes, int n_in,
                              void* d_out, int out_size, void* d_ws, size_t ws_size,
                              hipStream_t stream) {
    const float* z   = (const float*)d_in[0];
    const float* emb = (const float*)d_in[1];
    const float* cs  = (const float*)d_in[2];
    const float* ea  = (const float*)d_in[3];
    float* out = (float*)d_out;
    float* ws  = (float*)d_ws;

    float* esum    = ws + W_ESUM;
    int*   cnts    = (int*)(ws + W_CNT);
    float* enorm   = ws + W_ENORM;
    float* lossp   = ws + W_LOSSP;
    int*   curs    = (int*)(ws + W_CUR);
    float* wn      = ws + W_N;
    int*   widx    = (int*)(ws + W_IDX);
    int*   rsorted = (int*)(ws + W_SORT);

    // packed-B fp16 scratch in dead O_NEA output region (16B-aligned;
    // k_embed, the only writer of that region, runs last). 1MB.
    half_t* Bp = (half_t*)(out + O_NEA + 3);   // 524288 halfs

    k_prep2  <<<64, 256, 0, stream>>>(emb, enorm, Bp, ws);
    k_argmin <<<NBLK, 512, 0, stream>>>(z, Bp, enorm, emb,
                                        widx, out + O_IDX, out + O_ZQ, lossp, cnts);
    k_scan   <<<1, 256, 0, stream>>>(cs, cnts, lossp, out + O_NCS, curs,
                                     wn, out + O_LOSS);
    k_rank   <<<N_ROWS / 256, 256, 0, stream>>>(widx, curs, rsorted);
    k_esum2  <<<256, 256, 0, stream>>>(z, rsorted, widx, esum);
    k_embed  <<<KCODES, 256, 0, stream>>>(ea, esum, out + O_NCS, wn,
                                          out + O_NEA, out + O_NEMB);
}